// Round 14
// baseline (328.405 us; speedup 1.0000x reference)
//
#include <hip/hip_runtime.h>

#define VOCAB 21
#define EMB 128
#define H1 64
#define H2 100
#define T1 500
#define TP 100
#define NB 1024
#define TBL_LD 260
#define LOG2E 1.44269504f

typedef __attribute__((ext_vector_type(8))) short bf16x8;
typedef __attribute__((ext_vector_type(4))) float f32x4;

__device__ __forceinline__ unsigned short f2bf(float x){
    union { float f; unsigned u; } v; v.f = x;
    return (unsigned short)((v.u + 0x8000u) >> 16);
}
// LDS-only barrier: do NOT drain vmcnt (global stores/loads stay in flight)
__device__ __forceinline__ void bar_lds(){
    asm volatile("s_waitcnt lgkmcnt(0)\n\ts_barrier" ::: "memory");
}
__device__ __forceinline__ void wait_lds(){
    asm volatile("s_waitcnt lgkmcnt(0)" ::: "memory");
}
__device__ __forceinline__ float ex2(float x){ return __builtin_amdgcn_exp2f(x); }
__device__ __forceinline__ float rcp(float x){ return __builtin_amdgcn_rcpf(x); }

// ---------------------------------------------------------------------------
// Kernel 0: permuted xproj table, pre-scaled by log2(e).
// table[v][4*cell+gate] = LOG2E*(dot(W_ih1[gate*64+cell,:], emb[v,:]) + b_ih1 + b_hh1)
// ---------------------------------------------------------------------------
__global__ void k_table(const float* __restrict__ Wih, const float* __restrict__ emb,
                        const float* __restrict__ bih, const float* __restrict__ bhh,
                        float* __restrict__ table){
    const int p = threadIdx.x;
    const int v = blockIdx.x;
    const int orig = (p & 3) * H1 + (p >> 2);
    float s = bih[orig] + bhh[orig];
    if (v != 0){
        const float* w = Wih + orig * EMB;
        const float* e = emb + v * EMB;
        #pragma unroll 16
        for (int d = 0; d < EMB; ++d) s += w[d]*e[d];
    }
    table[v*TBL_LD + p] = s * LOG2E;
}

// ---------------------------------------------------------------------------
// Kernel 1: layer-1 LSTM. 8 rows/block, 128 blocks, 8 waves (2 tiles/wave).
// Zero junk + 1 update/lane: wave w owns tiles 2w,2w+1 (cells 8w..8w+7).
// Producer lanes (col n<8) write real quads to wave-private glds; consumer
// lane l reads slot 16*l -> (u=l>>5, cellIdx=(l>>3)&3, row=l&7). 2 waves/SIMD
// give TLP; 8-wave barrier. B cols 8..15 duplicate rows 0..7 (MFMA-only junk).
// ---------------------------------------------------------------------------
__global__ __launch_bounds__(512, 1) void k_lstm1(
    const int* __restrict__ xidx, const float* __restrict__ Whh,
    const float* __restrict__ tbl_g, unsigned short* __restrict__ x2b){
  __shared__ __align__(16) float table[VOCAB*TBL_LD];      // 21840 B
  __shared__ __align__(16) unsigned short hbuf[2][8*64];   // 2048 B (XOR-swizzled)
  __shared__ __align__(16) f32x4 glds[8][64];              // 8192 B wave-private
  __shared__ int idxs[8*T1];                               // 16000 B

  const int tid = threadIdx.x;
  const int w = tid >> 6, l = tid & 63;
  const int b0 = blockIdx.x * 8;
  const int n = l & 15, kg = l >> 4;

  for (int i = tid; i < VOCAB*TBL_LD; i += 512) table[i] = tbl_g[i];
  for (int i = tid; i < 8*T1; i += 512){
      int r = i / T1, t = i - r*T1;
      idxs[i] = xidx[(b0 + r)*T1 + t];
  }
  { unsigned short* hz = (unsigned short*)hbuf;
    for (int i = tid; i < 2048; i += 512) hz[i] = 0; }

  // A fragments (permuted Whh * LOG2E): tiles gt = 2w+u
  bf16x8 af[2][2];
  #pragma unroll
  for (int u = 0; u < 2; ++u){
      const int p = 16*(2*w + u) + n;
      const int orig = (p & 3)*H1 + (p >> 2);
      #pragma unroll
      for (int c = 0; c < 2; ++c){
          const float* src = Whh + orig*H1 + c*32 + kg*8;
          bf16x8 f;
          #pragma unroll
          for (int j = 0; j < 8; ++j) f[j] = (short)f2bf(src[j] * LOG2E);
          af[u][c] = f;
      }
  }

  char* hb = (char*)hbuf;
  char* gb = (char*)glds + 1024*w;
  // B-fragment reads (row = n&7; cols 8..15 duplicate = broadcast)
  const int rbr = n & 7;
  const int swzB = rbr << 4;
  const int rb0 = (rbr*128 + 16*kg) ^ swzB;
  const int rb1 = (rbr*128 + 64 + 16*kg) ^ swzB;
  // producer glds writes (only n<8): tile u quad (cellIdx=kg, row=n)
  const int gw0 = 128*kg + 16*(n & 7);
  const int gw1 = 512 + gw0;
  // consumer mapping: lane l -> u=l>>5, cellIdx=(l>>3)&3, row=l&7
  const int cell = 8*w + 4*(l >> 5) + ((l >> 3) & 3);
  const int row  = l & 7;
  const int wbh  = (row*128 + 2*cell) ^ (row << 4);
  const float twoL = 2.0f * LOG2E;

  float cc = 0.f, pm = -1e30f;
  __syncthreads();

  int vv = idxs[row*T1];
  f32x4 tq = *(const f32x4*)&table[vv*TBL_LD + 4*cell];
  int vnext = idxs[row*T1 + 1];
  const f32x4 z4 = {0.f, 0.f, 0.f, 0.f};

  int rp = 0, tm = 0, tp = 0;
  for (int t = 0; t < T1; ++t){
      bf16x8 bf0 = *(const bf16x8*)(hb + rp + rb0);
      bf16x8 bf1 = *(const bf16x8*)(hb + rp + rb1);
      f32x4 a0 = __builtin_amdgcn_mfma_f32_16x16x32_bf16(af[0][0], bf0, z4, 0,0,0);
      a0       = __builtin_amdgcn_mfma_f32_16x16x32_bf16(af[0][1], bf1, a0, 0,0,0);
      f32x4 a1 = __builtin_amdgcn_mfma_f32_16x16x32_bf16(af[1][0], bf0, z4, 0,0,0);
      a1       = __builtin_amdgcn_mfma_f32_16x16x32_bf16(af[1][1], bf1, a1, 0,0,0);
      if (n < 8){
          *(f32x4*)(gb + gw0) = a0;
          *(f32x4*)(gb + gw1) = a1;
      }
      wait_lds();
      f32x4 q = *(const f32x4*)(gb + 16*l);    // (i,f,g,o) of (cell, row)
      // off-chain prefetches for t+1
      f32x4 tqn = *(const f32x4*)&table[vnext*TBL_LD + 4*cell];
      int vn2 = idxs[row*T1 + ((t + 2 < T1) ? (t + 2) : 0)];
      float gi = q[0] + tq[0];
      float gf = q[1] + tq[1];
      float gg = q[2] + tq[2];
      float go = q[3] + tq[3];
      float si = rcp(1.f + ex2(-gi));
      float sf = rcp(1.f + ex2(-gf));
      float so = rcp(1.f + ex2(-go));
      float tg = 1.f - 2.f*rcp(1.f + ex2(gg + gg));
      cc = sf*cc + si*tg;
      float th = 1.f - 2.f*rcp(1.f + ex2(twoL*cc));
      float h = so*th;
      const int wp = rp ^ 1024;
      *(unsigned short*)(hb + wp + wbh) = f2bf(h);
      pm = fmaxf(pm, h);
      if (++tm == 5){
          x2b[(b0 + row)*(TP*H1) + tp*H1 + cell] = f2bf(pm);  // async bf16 store
          pm = -1e30f; tm = 0; ++tp;
      }
      tq = tqn; vnext = vn2;
      rp = wp;
      bar_lds();
  }
}

// ---------------------------------------------------------------------------
// Kernel 2: layer-2 LSTM (R13, unchanged). 4 rows/block, 256 blocks, 8 waves;
// x as register B-fragments from global bf16 (1-step prefetch); h in LDS.
// ---------------------------------------------------------------------------
__global__ __launch_bounds__(512, 1) void k_lstm2(
    const unsigned short* __restrict__ x2b, const float* __restrict__ Wih,
    const float* __restrict__ Whh, const float* __restrict__ bih,
    const float* __restrict__ bhh, const float* __restrict__ fcw,
    const float* __restrict__ fcb, float* __restrict__ out){
  __shared__ __align__(16) unsigned short blds[2][16*128];   // 8192 B (h only)
  __shared__ __align__(16) f32x4 gl2[108*4];                 // 6912 B [cell][row]
  __shared__ float fcred[8][4];

  const int tid = threadIdx.x;
  const int w = tid >> 6, l = tid & 63;
  const int b0 = blockIdx.x * 4;
  const int n = l & 15, kg = l >> 4;
  const int tlo = (w < 2) ? 4*w : 8 + 3*(w - 2);
  const int nt  = (w < 2) ? 4 : 3;

  { unsigned short* bz0 = (unsigned short*)blds;             // zero both h bufs
    for (int i = tid; i < 4096; i += 512) bz0[i] = 0; }
  { float* gz = (float*)gl2;
    for (int i = tid; i < 432*4; i += 512) gz[i] = 0.f; }

  // A fragments: [W_ih2 | W_hh2] permuted * LOG2E, zero-padded
  bf16x8 af[4][6];
  #pragma unroll
  for (int u = 0; u < 4; ++u){
      if (u < nt){
          const int p = 16*(tlo + u) + n;
          const int cell_ = p >> 2, gate = p & 3;
          #pragma unroll
          for (int c = 0; c < 6; ++c){
              bf16x8 f;
              #pragma unroll
              for (int jj = 0; jj < 8; ++jj){
                  int k = c*32 + kg*8 + jj;
                  float vv = 0.f;
                  if (cell_ < H2){
                      if (k < 64)           vv = Wih[(gate*H2 + cell_)*H1 + k];
                      else if (k < 64 + H2) vv = Whh[(gate*H2 + cell_)*H2 + (k - 64)];
                  }
                  f[jj] = (short)f2bf(vv * LOG2E);
              }
              af[u][c] = f;
          }
      }
  }

  // bias C-init quads (producer layout), * LOG2E
  f32x4 bz[4];
  #pragma unroll
  for (int u = 0; u < 4; ++u){
      const int cu = 4*(tlo + u) + kg;
      f32x4 b = {0.f,0.f,0.f,0.f};
      if (u < nt && cu < H2){
          #pragma unroll
          for (int g = 0; g < 4; ++g) b[g] = (bih[g*H2 + cu] + bhh[g*H2 + cu]) * LOG2E;
      }
      bz[u] = b;
  }

  // consumer: lane l -> cell = 4*tlo + (l>>2), row = l&3; active if in-range
  const bool act = (l >> 2) < 4*nt;
  const int cellc = 4*tlo + (l >> 2);
  const int r_c = l & 3;
  const float fwv = (act && cellc < H2) ? fcw[cellc] : 0.f;
  const float twoL = 2.0f * LOG2E;

  char* bb = (char*)blds;
  char* gb = (char*)gl2;
  // h-fragment reads: k = 64 + (j*32 + kg*8), j=0..3 -> h index j*32+kg*8
  int rbh[4];
  #pragma unroll
  for (int j = 0; j < 4; ++j)
      rbh[j] = (n*256 + 2*(j*32 + 8*kg)) ^ ((n & 7) << 4);
  const int wbh = (r_c*256 + 2*cellc) ^ ((r_c & 7) << 4);

  // x B-fragments straight from global (bf16), row-clamped for junk cols
  const int nr = n & 3;
  const unsigned short* xrow = x2b + (b0 + nr)*(TP*H1) + kg*8;
  bf16x8 x0 = *(const bf16x8*)(xrow);          // t=0, k=0..31 chunk
  bf16x8 x1 = *(const bf16x8*)(xrow + 32);     // t=0, k=32..63 chunk
  float cc = 0.f, hv = 0.f;
  __syncthreads();

  int rp = 0;
  for (int t = 0; t < TP; ++t){
      bf16x8 xn0, xn1;
      if (t + 1 < TP){                         // prefetch next step's x frags
          xn0 = *(const bf16x8*)(xrow + (t+1)*H1);
          xn1 = *(const bf16x8*)(xrow + (t+1)*H1 + 32);
      }
      bf16x8 h0 = *(const bf16x8*)(bb + rp + rbh[0]);
      bf16x8 h1 = *(const bf16x8*)(bb + rp + rbh[1]);
      bf16x8 h2 = *(const bf16x8*)(bb + rp + rbh[2]);
      bf16x8 h3 = *(const bf16x8*)(bb + rp + rbh[3]);
      #pragma unroll
      for (int u = 0; u < 4; ++u){
          if (u < nt){
              f32x4 za = __builtin_amdgcn_mfma_f32_16x16x32_bf16(af[u][0], x0, bz[u], 0,0,0);
              f32x4 zb = __builtin_amdgcn_mfma_f32_16x16x32_bf16(af[u][1], x1, (f32x4){0.f,0.f,0.f,0.f}, 0,0,0);
              za = __builtin_amdgcn_mfma_f32_16x16x32_bf16(af[u][2], h0, za, 0,0,0);
              zb = __builtin_amdgcn_mfma_f32_16x16x32_bf16(af[u][3], h1, zb, 0,0,0);
              za = __builtin_amdgcn_mfma_f32_16x16x32_bf16(af[u][4], h2, za, 0,0,0);
              zb = __builtin_amdgcn_mfma_f32_16x16x32_bf16(af[u][5], h3, zb, 0,0,0);
              f32x4 z = za + zb;
              if (n < 4)                        // cell 4*(tlo+u)+kg, row n
                  *(f32x4*)(gb + 256*(tlo + u) + 64*kg + 16*n) = z;
          }
      }
      wait_lds();
      const int wp = rp ^ 4096;
      if (act){
          f32x4 q = *(const f32x4*)(gb + 256*tlo + 16*l);
          float si = rcp(1.f + ex2(-q[0]));
          float sf = rcp(1.f + ex2(-q[1]));
          float so = rcp(1.f + ex2(-q[3]));
          float tg = 1.f - 2.f*rcp(1.f + ex2(q[2] + q[2]));
          cc = sf*cc + si*tg;
          float th = 1.f - 2.f*rcp(1.f + ex2(twoL*cc));
          hv = so*th;
          *(unsigned short*)(bb + wp + wbh) = f2bf(hv);  // k>=164 weights are 0
      }
      x0 = xn0; x1 = xn1;
      rp = wp;
      bar_lds();
  }

  // FC + sigmoid: p=0 on junk lanes, reduce cells then waves
  float p = (act && cellc < H2) ? hv * fwv : 0.f;
  p += __shfl_xor(p, 4);
  p += __shfl_xor(p, 8);
  p += __shfl_xor(p, 16);
  p += __shfl_xor(p, 32);
  if (l < 4) fcred[w][l] = p;
  __syncthreads();
  if (tid < 4){
      float s = 0.f;
      #pragma unroll
      for (int ww = 0; ww < 8; ++ww) s += fcred[ww][tid];
      s += fcb[0];
      out[b0 + tid] = rcp(1.f + ex2(-s * LOG2E));
  }
}

// ---------------------------------------------------------------------------
extern "C" void kernel_launch(void* const* d_in, const int* in_sizes, int n_in,
                              void* d_out, int out_size, void* d_ws, size_t ws_size,
                              hipStream_t stream) {
    const int*   x_idx = (const int*)  d_in[0];
    const float* emb   = (const float*)d_in[1];
    const float* Wih1  = (const float*)d_in[2];
    const float* Whh1  = (const float*)d_in[3];
    const float* bih1  = (const float*)d_in[4];
    const float* bhh1  = (const float*)d_in[5];
    const float* Wih2  = (const float*)d_in[6];
    const float* Whh2  = (const float*)d_in[7];
    const float* bih2  = (const float*)d_in[8];
    const float* bhh2  = (const float*)d_in[9];
    const float* fcw   = (const float*)d_in[10];
    const float* fcb   = (const float*)d_in[11];
    float* out = (float*)d_out;

    float*          table = (float*)d_ws;                    // 21840 B
    unsigned short* x2b   = (unsigned short*)((char*)d_ws + 32768); // 13.1 MB bf16

    k_table<<<VOCAB, 256, 0, stream>>>(Wih1, emb, bih1, bhh1, table);
    k_lstm1<<<NB / 8, 512, 0, stream>>>(x_idx, Whh1, table, x2b);
    k_lstm2<<<NB / 4, 512, 0, stream>>>(x2b, Wih2, Whh2, bih2, bhh2, fcw, fcb, out);
}

// Round 15
// 312.276 us; speedup vs baseline: 1.0517x; 1.0517x over previous
//
#include <hip/hip_runtime.h>

#define VOCAB 21
#define EMB 128
#define H1 64
#define H2 100
#define T1 500
#define TP 100
#define NB 1024
#define TBL_LD 260
#define LOG2E 1.44269504f

typedef __attribute__((ext_vector_type(8))) short bf16x8;
typedef __attribute__((ext_vector_type(4))) float f32x4;

__device__ __forceinline__ unsigned short f2bf(float x){
    union { float f; unsigned u; } v; v.f = x;
    return (unsigned short)((v.u + 0x8000u) >> 16);
}
// LDS-only barrier: do NOT drain vmcnt (global stores/loads stay in flight)
__device__ __forceinline__ void bar_lds(){
    asm volatile("s_waitcnt lgkmcnt(0)\n\ts_barrier" ::: "memory");
}
__device__ __forceinline__ float ex2(float x){ return __builtin_amdgcn_exp2f(x); }
__device__ __forceinline__ float rcp(float x){ return __builtin_amdgcn_rcpf(x); }

// ---------------------------------------------------------------------------
// Kernel 0: permuted xproj table, pre-scaled by log2(e).
// table[v][4*cell+gate] = LOG2E*(dot(W_ih1[gate*64+cell,:], emb[v,:]) + b_ih1 + b_hh1)
// ---------------------------------------------------------------------------
__global__ void k_table(const float* __restrict__ Wih, const float* __restrict__ emb,
                        const float* __restrict__ bih, const float* __restrict__ bhh,
                        float* __restrict__ table){
    const int p = threadIdx.x;
    const int v = blockIdx.x;
    const int orig = (p & 3) * H1 + (p >> 2);
    float s = bih[orig] + bhh[orig];
    if (v != 0){
        const float* w = Wih + orig * EMB;
        const float* e = emb + v * EMB;
        #pragma unroll 16
        for (int d = 0; d < EMB; ++d) s += w[d]*e[d];
    }
    table[v*TBL_LD + p] = s * LOG2E;
}

// ---------------------------------------------------------------------------
// Kernel 1: layer-1 LSTM (R12, proven). 16 rows/block, 64 blocks, 16 waves
// (1 tile/wave). Zero junk, zero redistribute: lane l of wave gt holds
// (i,f,g,o) of (cell = 4*gt + (l>>4), row = l&15) straight from the MFMA acc.
// xproj quad = MFMA C-init. Output x2 stored bf16.
// ---------------------------------------------------------------------------
__global__ __launch_bounds__(1024, 1) void k_lstm1(
    const int* __restrict__ xidx, const float* __restrict__ Whh,
    const float* __restrict__ tbl_g, unsigned short* __restrict__ x2b){
  __shared__ __align__(16) float table[VOCAB*TBL_LD];      // 21840 B
  __shared__ __align__(16) unsigned short hbuf[2][16*64];  // 4096 B (XOR-swizzled)
  __shared__ int idxs[16*T1];                              // 32000 B

  const int tid = threadIdx.x;
  const int gt = tid >> 6, l = tid & 63;     // wave == tile
  const int b0 = blockIdx.x * 16;
  const int row = l & 15, kg = l >> 4;

  for (int i = tid; i < VOCAB*TBL_LD; i += 1024) table[i] = tbl_g[i];
  for (int i = tid; i < 16*T1; i += 1024){
      int r = i / T1, t = i - r*T1;
      idxs[i] = xidx[(b0 + r)*T1 + t];
  }
  { unsigned short* hz = (unsigned short*)hbuf;
    for (int i = tid; i < 2048; i += 1024) hz[i] = 0; }

  // A fragments (permuted Whh * LOG2E): single tile gt, 8 VGPRs
  bf16x8 af0, af1;
  {
      const int p = 16*gt + row;
      const int orig = (p & 3)*H1 + (p >> 2);
      bf16x8 f;
      const float* s0 = Whh + orig*H1 + kg*8;
      #pragma unroll
      for (int j = 0; j < 8; ++j) f[j] = (short)f2bf(s0[j] * LOG2E);
      af0 = f;
      const float* s1 = Whh + orig*H1 + 32 + kg*8;
      #pragma unroll
      for (int j = 0; j < 8; ++j) f[j] = (short)f2bf(s1[j] * LOG2E);
      af1 = f;
  }

  char* hb = (char*)hbuf;
  const int swz = (row & 7) << 4;
  const int rb0 = (row*128 + 16*kg) ^ swz;
  const int rb1 = (row*128 + 64 + 16*kg) ^ swz;
  const int cell = 4*gt + kg;                       // this lane's cell
  const int wbh  = (row*128 + 2*cell) ^ swz;
  const float twoL = 2.0f * LOG2E;

  float cc = 0.f, pm = -1e30f;
  __syncthreads();

  int vv = idxs[row*T1];
  f32x4 tq = *(const f32x4*)&table[vv*TBL_LD + 4*cell];
  int vnext = idxs[row*T1 + 1];

  int rp = 0, tm = 0, tp = 0;
  for (int t = 0; t < T1; ++t){
      bf16x8 bf0 = *(const bf16x8*)(hb + rp + rb0);
      bf16x8 bf1 = *(const bf16x8*)(hb + rp + rb1);
      f32x4 a = __builtin_amdgcn_mfma_f32_16x16x32_bf16(af0, bf0, tq, 0,0,0);
      f32x4 z = __builtin_amdgcn_mfma_f32_16x16x32_bf16(af1, bf1, a, 0,0,0);
      // off-chain prefetches for t+1
      f32x4 tqn = *(const f32x4*)&table[vnext*TBL_LD + 4*cell];
      int vn2 = idxs[row*T1 + ((t + 2 < T1) ? (t + 2) : 0)];
      // gates: z = (i,f,g,o) for (cell,row), pre-scaled by log2e
      float si = rcp(1.f + ex2(-z[0]));
      float sf = rcp(1.f + ex2(-z[1]));
      float so = rcp(1.f + ex2(-z[3]));
      float tg = 1.f - 2.f*rcp(1.f + ex2(z[2] + z[2]));
      cc = sf*cc + si*tg;
      float th = 1.f - 2.f*rcp(1.f + ex2(twoL*cc));
      float h = so*th;
      const int wp = rp ^ 2048;
      *(unsigned short*)(hb + wp + wbh) = f2bf(h);
      pm = fmaxf(pm, h);
      if (++tm == 5){
          x2b[(b0 + row)*(TP*H1) + tp*H1 + cell] = f2bf(pm);  // async bf16 store
          pm = -1e30f; tm = 0; ++tp;
      }
      tq = tqn; vnext = vn2;
      rp = wp;
      bar_lds();
  }
}

// ---------------------------------------------------------------------------
// Kernel 2: layer-2 LSTM. 16 rows/block, 64 blocks, 8 waves; 26 tiles split
// 4,4,3,3,3,3,3,3. PRODUCER-DIRECT: all 16 MFMA cols are real rows, so lane l
// of tile tlo+u holds the (i,f,g,o) quad of (cell=4*(tlo+u)+kg, row=l&15) —
// no redistribute, no junk; nt real updates/lane. x per-lane from global
// bf16 (1-step prefetch); h ping-pongs in LDS (16x128 bf16, swizzled).
// ---------------------------------------------------------------------------
__global__ __launch_bounds__(512, 1) void k_lstm2(
    const unsigned short* __restrict__ x2b, const float* __restrict__ Wih,
    const float* __restrict__ Whh, const float* __restrict__ bih,
    const float* __restrict__ bhh, const float* __restrict__ fcw,
    const float* __restrict__ fcb, float* __restrict__ out){
  __shared__ __align__(16) unsigned short blds[2][16*128];   // 8192 B (h only)
  __shared__ float fcred[8][16];

  const int tid = threadIdx.x;
  const int w = tid >> 6, l = tid & 63;
  const int b0 = blockIdx.x * 16;
  const int n = l & 15, kg = l >> 4;
  const int tlo = (w < 2) ? 4*w : 8 + 3*(w - 2);
  const int nt  = (w < 2) ? 4 : 3;

  { unsigned short* bz0 = (unsigned short*)blds;             // zero both h bufs
    for (int i = tid; i < 4096; i += 512) bz0[i] = 0; }

  // A fragments: [W_ih2 | W_hh2] permuted * LOG2E, zero-padded
  bf16x8 af[4][6];
  #pragma unroll
  for (int u = 0; u < 4; ++u){
      if (u < nt){
          const int p = 16*(tlo + u) + n;
          const int cell_ = p >> 2, gate = p & 3;
          #pragma unroll
          for (int c = 0; c < 6; ++c){
              bf16x8 f;
              #pragma unroll
              for (int jj = 0; jj < 8; ++jj){
                  int k = c*32 + kg*8 + jj;
                  float vv = 0.f;
                  if (cell_ < H2){
                      if (k < 64)           vv = Wih[(gate*H2 + cell_)*H1 + k];
                      else if (k < 64 + H2) vv = Whh[(gate*H2 + cell_)*H2 + (k - 64)];
                  }
                  f[jj] = (short)f2bf(vv * LOG2E);
              }
              af[u][c] = f;
          }
      }
  }

  // bias C-init quads + per-cell constants (producer layout: cell=4(tlo+u)+kg)
  f32x4 bz[4];
  int cu[4], wbh[4];
  float fw[4];
  #pragma unroll
  for (int u = 0; u < 4; ++u){
      cu[u] = 4*(tlo + u) + kg;
      f32x4 b = {0.f,0.f,0.f,0.f};
      float fv = 0.f;
      if (u < nt && cu[u] < H2){
          #pragma unroll
          for (int g = 0; g < 4; ++g) b[g] = (bih[g*H2 + cu[u]] + bhh[g*H2 + cu[u]]) * LOG2E;
          fv = fcw[cu[u]];
      }
      bz[u] = b; fw[u] = fv;
      wbh[u] = (n*256 + 2*cu[u]) ^ ((n & 7) << 4);
  }
  const float twoL = 2.0f * LOG2E;

  char* bb = (char*)blds;
  // h B-fragment reads: chunk j (k=64+j*32+8kg+..) from row n
  int rbh[4];
  #pragma unroll
  for (int j = 0; j < 4; ++j)
      rbh[j] = (n*256 + 2*(j*32 + 8*kg)) ^ ((n & 7) << 4);

  // x B-fragments straight from global (bf16): lane's own row n
  const unsigned short* xrow = x2b + (b0 + n)*(TP*H1) + kg*8;
  bf16x8 x0 = *(const bf16x8*)(xrow);          // t=0, k chunk 0
  bf16x8 x1 = *(const bf16x8*)(xrow + 32);     // t=0, k chunk 1
  float cc[4] = {0.f,0.f,0.f,0.f};
  float hv[4] = {0.f,0.f,0.f,0.f};
  __syncthreads();

  int rp = 0;
  for (int t = 0; t < TP; ++t){
      bf16x8 xn0, xn1;
      if (t + 1 < TP){                         // prefetch next step's x frags
          xn0 = *(const bf16x8*)(xrow + (t+1)*H1);
          xn1 = *(const bf16x8*)(xrow + (t+1)*H1 + 32);
      }
      bf16x8 h0 = *(const bf16x8*)(bb + rp + rbh[0]);
      bf16x8 h1 = *(const bf16x8*)(bb + rp + rbh[1]);
      bf16x8 h2 = *(const bf16x8*)(bb + rp + rbh[2]);
      bf16x8 h3 = *(const bf16x8*)(bb + rp + rbh[3]);
      const int wp = rp ^ 4096;
      #pragma unroll
      for (int u = 0; u < 4; ++u){
          if (u < nt){
              f32x4 za = __builtin_amdgcn_mfma_f32_16x16x32_bf16(af[u][0], x0, bz[u], 0,0,0);
              f32x4 zb = __builtin_amdgcn_mfma_f32_16x16x32_bf16(af[u][1], x1, (f32x4){0.f,0.f,0.f,0.f}, 0,0,0);
              za = __builtin_amdgcn_mfma_f32_16x16x32_bf16(af[u][2], h0, za, 0,0,0);
              zb = __builtin_amdgcn_mfma_f32_16x16x32_bf16(af[u][3], h1, zb, 0,0,0);
              za = __builtin_amdgcn_mfma_f32_16x16x32_bf16(af[u][4], h2, za, 0,0,0);
              zb = __builtin_amdgcn_mfma_f32_16x16x32_bf16(af[u][5], h3, zb, 0,0,0);
              f32x4 z = za + zb;
              // producer-direct update: (cell cu[u], row n)
              float si = rcp(1.f + ex2(-z[0]));
              float sf = rcp(1.f + ex2(-z[1]));
              float so = rcp(1.f + ex2(-z[3]));
              float tg = 1.f - 2.f*rcp(1.f + ex2(z[2] + z[2]));
              cc[u] = sf*cc[u] + si*tg;
              float th = 1.f - 2.f*rcp(1.f + ex2(twoL*cc[u]));
              hv[u] = so*th;
              if (cu[u] < H2)
                  *(unsigned short*)(bb + wp + wbh[u]) = f2bf(hv[u]);
          }
      }
      x0 = xn0; x1 = xn1;
      rp = wp;
      bar_lds();
  }

  // FC + sigmoid: lane sums its cells (row n), reduce kg groups, then waves
  float p = 0.f;
  #pragma unroll
  for (int u = 0; u < 4; ++u)
      if (u < nt && cu[u] < H2) p += hv[u] * fw[u];
  p += __shfl_xor(p, 16);
  p += __shfl_xor(p, 32);
  if (l < 16) fcred[w][l] = p;
  __syncthreads();
  if (tid < 16){
      float s = 0.f;
      #pragma unroll
      for (int ww = 0; ww < 8; ++ww) s += fcred[ww][tid];
      s += fcb[0];
      out[b0 + tid] = rcp(1.f + ex2(-s * LOG2E));
  }
}

// ---------------------------------------------------------------------------
extern "C" void kernel_launch(void* const* d_in, const int* in_sizes, int n_in,
                              void* d_out, int out_size, void* d_ws, size_t ws_size,
                              hipStream_t stream) {
    const int*   x_idx = (const int*)  d_in[0];
    const float* emb   = (const float*)d_in[1];
    const float* Wih1  = (const float*)d_in[2];
    const float* Whh1  = (const float*)d_in[3];
    const float* bih1  = (const float*)d_in[4];
    const float* bhh1  = (const float*)d_in[5];
    const float* Wih2  = (const float*)d_in[6];
    const float* Whh2  = (const float*)d_in[7];
    const float* bih2  = (const float*)d_in[8];
    const float* bhh2  = (const float*)d_in[9];
    const float* fcw   = (const float*)d_in[10];
    const float* fcb   = (const float*)d_in[11];
    float* out = (float*)d_out;

    float*          table = (float*)d_ws;                    // 21840 B
    unsigned short* x2b   = (unsigned short*)((char*)d_ws + 32768); // 13.1 MB bf16

    k_table<<<VOCAB, 256, 0, stream>>>(Wih1, emb, bih1, bhh1, table);
    k_lstm1<<<NB / 16, 1024, 0, stream>>>(x_idx, Whh1, table, x2b);
    k_lstm2<<<NB / 16, 512, 0, stream>>>(x2b, Wih2, Whh2, bih2, bhh2, fcw, fcb, out);
}